// Round 6
// baseline (816.315 us; speedup 1.0000x reference)
//
#include <hip/hip_runtime.h>
#include <hip/hip_bf16.h>
#include <cmath>

// ---------------------------------------------------------------------------
// Problem constants (B=1, T=2048, D=768, H=4, N=25600, KD=128, HQ=512,
// HID_A=44, HID_S=1024, KNN=16)
// ---------------------------------------------------------------------------
#define NEG_INF (-3.402823466e38f)
#define SPLITS 64          // N-splits per head
#define SPN    400         // experts per split
#define GRP    16          // experts per staged LDS group (one MFMA A-tile)
#define NGRP   25          // groups per split (400/16)

typedef __attribute__((ext_vector_type(8))) short s16x8;   // 8 bf16 (4 VGPRs)
typedef __attribute__((ext_vector_type(4))) float f32x4;   // MFMA C/D frag

__device__ __forceinline__ unsigned short f2bf(float f) {
    union { float f; unsigned u; } v; v.f = f;
    unsigned u = v.u;
    u += 0x7fffu + ((u >> 16) & 1u);   // round-to-nearest-even
    return (unsigned short)(u >> 16);
}

// ---------------------------------------------------------------------------
// One fused fp32->bf16 convert for ALL tensors: {x, wq, sw1, sw3, sw2} into
// ws[0..8650752) and keys into ws[8650752..34865152) (adjacent dst regions).
// Indexing in ushort4 (=float4-src) units.
// ---------------------------------------------------------------------------
__global__ __launch_bounds__(256) void cvt_all_kernel(
        const float* __restrict__ s0, const float* __restrict__ s1,
        const float* __restrict__ s2, const float* __restrict__ s3,
        const float* __restrict__ s4, const float* __restrict__ keys,
        unsigned short* __restrict__ dst) {
    int i = blockIdx.x * 256 + threadIdx.x;
    if (i >= 4358144) return;                      // 1081344 small + 3276800 keys
    const float* src; int base;
    if      (i < 393216)  { src = s0;   base = 0; }
    else if (i < 491520)  { src = s1;   base = 393216; }
    else if (i < 688128)  { src = s2;   base = 491520; }
    else if (i < 884736)  { src = s3;   base = 688128; }
    else if (i < 1081344) { src = s4;   base = 884736; }
    else                  { src = keys; base = 1081344; }
    float4 f = ((const float4*)src)[i - base];
    ushort4 o;
    o.x = f2bf(f.x); o.y = f2bf(f.y); o.z = f2bf(f.z); o.w = f2bf(f.w);
    ((ushort4*)dst)[i] = o;
}

// ---------------------------------------------------------------------------
// per-token row sum of x (fp32), one wave per token
// ---------------------------------------------------------------------------
__global__ __launch_bounds__(256) void row_sum_kernel(
        const float* __restrict__ x, float* __restrict__ sumx) {
    int gw = (blockIdx.x * 256 + threadIdx.x) >> 6;   // token id (grid sized exact)
    int lane = threadIdx.x & 63;
    const float* row = x + (size_t)gw * 768;
    float s = 0.f;
    #pragma unroll
    for (int k = 0; k < 12; ++k) s += row[lane + k * 64];
    #pragma unroll
    for (int off = 32; off > 0; off >>= 1) s += __shfl_down(s, off);
    if (lane == 0) sumx[gw] = s;
}

// ---------------------------------------------------------------------------
// GEMM  C = A @ W^T  (A: MxK bf16 row-major, W: NxK bf16 row-major)
// 64x64 tile, BK=64, 256 threads (4 waves in 2x2), 16x16x32 bf16 MFMA.
// EPI 0: q-projection epilogue (+bq, BatchNorm) -> bf16 outB
// EPI 2: final epilogue (+combsum[m]) -> fp32 outF
// ---------------------------------------------------------------------------
template <int EPI>
__global__ __launch_bounds__(256) void gemm_nt(
        const unsigned short* __restrict__ A, const unsigned short* __restrict__ W,
        int M, int N, int K,
        float* __restrict__ outF, unsigned short* __restrict__ outB,
        const float* __restrict__ p0, const float* __restrict__ p1,
        const float* __restrict__ p2, const float* __restrict__ p3,
        const float* __restrict__ p4) {
    __shared__ alignas(16) short As[64][72];   // +8 bf16 pad: 144B stride, 16B-aligned rows
    __shared__ alignas(16) short Ws[64][72];
    const int tid = threadIdx.x;
    const int m0 = blockIdx.x * 64, n0 = blockIdx.y * 64;
    const int wv = tid >> 6, lane = tid & 63;
    const int wr = wv >> 1, wc = wv & 1;
    const int lr = lane & 15, lq = lane >> 4;
    f32x4 acc[2][2];
    #pragma unroll
    for (int i = 0; i < 2; ++i)
        #pragma unroll
        for (int j = 0; j < 2; ++j) acc[i][j] = (f32x4){0.f, 0.f, 0.f, 0.f};

    for (int kb = 0; kb < K; kb += 64) {
        #pragma unroll
        for (int it = 0; it < 2; ++it) {            // 512 chunks of 8 bf16
            int chunk = tid + it * 256;
            int row = chunk >> 3, c8 = (chunk & 7) * 8;
            *(s16x8*)&As[row][c8] = *(const s16x8*)(A + (size_t)(m0 + row) * K + kb + c8);
            *(s16x8*)&Ws[row][c8] = *(const s16x8*)(W + (size_t)(n0 + row) * K + kb + c8);
        }
        __syncthreads();
        #pragma unroll
        for (int ks = 0; ks < 2; ++ks) {
            const int k0 = ks * 32 + lq * 8;
            #pragma unroll
            for (int rt = 0; rt < 2; ++rt) {
                s16x8 a = *(const s16x8*)&As[wr * 32 + rt * 16 + lr][k0];
                #pragma unroll
                for (int ct = 0; ct < 2; ++ct) {
                    s16x8 b = *(const s16x8*)&Ws[wc * 32 + ct * 16 + lr][k0];
                    acc[rt][ct] = __builtin_amdgcn_mfma_f32_16x16x32_bf16(a, b, acc[rt][ct], 0, 0, 0);
                }
            }
        }
        __syncthreads();
    }
    // C/D layout: col = lane&15, row = (lane>>4)*4 + r  [verified m89/m91]
    #pragma unroll
    for (int rt = 0; rt < 2; ++rt)
        #pragma unroll
        for (int ct = 0; ct < 2; ++ct)
            #pragma unroll
            for (int r = 0; r < 4; ++r) {
                int m = m0 + wr * 32 + rt * 16 + lq * 4 + r;
                int n = n0 + wc * 32 + ct * 16 + lr;
                float v = acc[rt][ct][r];
                if (EPI == 0) {
                    float q = v + p0[n];
                    q = (q - p3[n]) * rsqrtf(p4[n] + 1e-5f) * p1[n] + p2[n];
                    outB[(size_t)m * N + n] = f2bf(q);
                } else {
                    outF[(size_t)m * N + n] = v + p0[m];
                }
            }
}

// ---------------------------------------------------------------------------
// Dense SwiGLU up: h = silu(x@W1^T) * (x@W3^T) -> bf16, dual accumulators
// ---------------------------------------------------------------------------
__global__ __launch_bounds__(256) void gemm_swiglu_kernel(
        const unsigned short* __restrict__ A, const unsigned short* __restrict__ W1,
        const unsigned short* __restrict__ W3, int M, int N, int K,
        unsigned short* __restrict__ outB) {
    __shared__ alignas(16) short As[64][72];
    __shared__ alignas(16) short W1s[64][72];
    __shared__ alignas(16) short W3s[64][72];
    const int tid = threadIdx.x;
    const int m0 = blockIdx.x * 64, n0 = blockIdx.y * 64;
    const int wv = tid >> 6, lane = tid & 63;
    const int wr = wv >> 1, wc = wv & 1;
    const int lr = lane & 15, lq = lane >> 4;
    f32x4 acc1[2][2], acc3[2][2];
    #pragma unroll
    for (int i = 0; i < 2; ++i)
        #pragma unroll
        for (int j = 0; j < 2; ++j) {
            acc1[i][j] = (f32x4){0.f, 0.f, 0.f, 0.f};
            acc3[i][j] = (f32x4){0.f, 0.f, 0.f, 0.f};
        }
    for (int kb = 0; kb < K; kb += 64) {
        #pragma unroll
        for (int it = 0; it < 2; ++it) {
            int chunk = tid + it * 256;
            int row = chunk >> 3, c8 = (chunk & 7) * 8;
            *(s16x8*)&As[row][c8]  = *(const s16x8*)(A  + (size_t)(m0 + row) * K + kb + c8);
            *(s16x8*)&W1s[row][c8] = *(const s16x8*)(W1 + (size_t)(n0 + row) * K + kb + c8);
            *(s16x8*)&W3s[row][c8] = *(const s16x8*)(W3 + (size_t)(n0 + row) * K + kb + c8);
        }
        __syncthreads();
        #pragma unroll
        for (int ks = 0; ks < 2; ++ks) {
            const int k0 = ks * 32 + lq * 8;
            #pragma unroll
            for (int rt = 0; rt < 2; ++rt) {
                s16x8 a = *(const s16x8*)&As[wr * 32 + rt * 16 + lr][k0];
                #pragma unroll
                for (int ct = 0; ct < 2; ++ct) {
                    s16x8 b1 = *(const s16x8*)&W1s[wc * 32 + ct * 16 + lr][k0];
                    s16x8 b3 = *(const s16x8*)&W3s[wc * 32 + ct * 16 + lr][k0];
                    acc1[rt][ct] = __builtin_amdgcn_mfma_f32_16x16x32_bf16(a, b1, acc1[rt][ct], 0, 0, 0);
                    acc3[rt][ct] = __builtin_amdgcn_mfma_f32_16x16x32_bf16(a, b3, acc3[rt][ct], 0, 0, 0);
                }
            }
        }
        __syncthreads();
    }
    #pragma unroll
    for (int rt = 0; rt < 2; ++rt)
        #pragma unroll
        for (int ct = 0; ct < 2; ++ct)
            #pragma unroll
            for (int r = 0; r < 4; ++r) {
                int m = m0 + wr * 32 + rt * 16 + lq * 4 + r;
                int n = n0 + wc * 32 + ct * 16 + lr;
                float u1 = acc1[rt][ct][r], u3 = acc3[rt][ct][r];
                float hv = u1 / (1.f + expf(-u1)) * u3;
                outB[(size_t)m * N + n] = f2bf(hv);
            }
}

// ---------------------------------------------------------------------------
// Score pass kernel (both passes share the body -> bitwise-identical scores).
// A = K (experts = rows), B = Q (tokens = cols): each lane's 4 acc values
// belong to ONE token. Q register-resident.
//
// __launch_bounds__(256, 4) is LOAD-BEARING: without it the compiler takes
// the full 256-VGPR budget (r5: VGPR=256, occupancy 10.5%, +10% dur). With
// it: <=128 VGPR -> 4 blocks/CU resident, and the 8 token-tile blocks that
// share a (h,sp) key stream run concurrently -> L2 reuse of the key tile.
//
// Per wave per group: 1 bf16 16B staging load + 1 ds_write_b128 +
// 4 ds_read_b128 + 16 MFMA + max-fold, double-buffered LDS (8.7 KB).
//
// PASS 1: per-(lane,token) running max -> maxbuf (256 disjoint cell-maxima
//         per (t,h): cell = (sp, lq), 25 groups x 4 rows = 100 experts).
// PASS 2: recompute scores, keep (v,idx) with v >= theta[t,h] via atomic
//         compaction (expected ~16-20 survivors, cap 64).
// ---------------------------------------------------------------------------
template <int PASS>
__global__ __launch_bounds__(256, 4) void score_pass_kernel(
        const unsigned short* __restrict__ Q,    // 2048 x 512 bf16
        const unsigned short* __restrict__ Kt,   // 4 x 25600 x 128 bf16
        float* __restrict__ maxbuf,              // [8192][256]  (pass 1 out)
        const float* __restrict__ theta,         // [8192]       (pass 2 in)
        int* __restrict__ cnt,                   // [8192]       (pass 2)
        float2* __restrict__ buf) {              // [8192][64]   (pass 2 out)
    __shared__ alignas(16) short Ks[2][GRP][136];   // 2 x 16 x 272B = 8.7 KB
    const int b = blockIdx.x;
    const int tile = b >> 8;                     // 256 = 4 heads x 64 splits
    const int hsp = b & 255;
    const int h = hsp >> 6, sp = hsp & 63;
    const int w = threadIdx.x >> 6, lane = threadIdx.x & 63;
    const int lr = lane & 15, lq = lane >> 4;
    const int t0 = tile * 256 + w * 64;
    const int nb0 = sp * SPN;

    // Q fragments: 4 token-tiles x 4 k-steps, register-resident
    s16x8 qf[4][4];
    #pragma unroll
    for (int tt = 0; tt < 4; ++tt) {
        const unsigned short* qp = Q + (size_t)(t0 + tt * 16 + lr) * 512 + h * 128 + lq * 8;
        #pragma unroll
        for (int ks = 0; ks < 4; ++ks) qf[tt][ks] = *(const s16x8*)(qp + ks * 32);
    }

    float runmax[4] = {NEG_INF, NEG_INF, NEG_INF, NEG_INF};
    float th[4];
    if (PASS == 2) {
        #pragma unroll
        for (int tt = 0; tt < 4; ++tt) th[tt] = theta[(t0 + tt * 16 + lr) * 4 + h];
    }

    // Staging: thread (srow, scol) covers one 16B chunk of the 16x128 group.
    const int srow = threadIdx.x >> 4;           // 0..15
    const int scol = (threadIdx.x & 15) * 8;     // bf16 elem 0..120
    const unsigned short* kgp =
        Kt + ((size_t)h * 25600 + nb0 + srow) * 128 + scol;
    // group stride = 16 rows * 128 = 2048 bf16

    // prologue: stage group 0 into buffer 0
    *(s16x8*)&Ks[0][srow][scol] = *(const s16x8*)kgp;

    for (int g = 0; g < NGRP; ++g) {
        // issue global load for group g+1 (consumed after this group's MFMAs)
        s16x8 kst;
        if (g + 1 < NGRP) kst = *(const s16x8*)(kgp + (size_t)(g + 1) * 2048);
        __syncthreads();                          // buf[g&1] ready for all waves
        const int cb = g & 1;
        f32x4 acc[4];
        #pragma unroll
        for (int tt = 0; tt < 4; ++tt) acc[tt] = (f32x4){0.f, 0.f, 0.f, 0.f};
        #pragma unroll
        for (int ks = 0; ks < 4; ++ks) {
            s16x8 ka = *(const s16x8*)&Ks[cb][lr][ks * 32 + lq * 8];
            #pragma unroll
            for (int tt = 0; tt < 4; ++tt)
                acc[tt] = __builtin_amdgcn_mfma_f32_16x16x32_bf16(ka, qf[tt][ks], acc[tt], 0, 0, 0);
        }
        if (PASS == 1) {
            #pragma unroll
            for (int tt = 0; tt < 4; ++tt) {
                float m0 = fmaxf(fmaxf(acc[tt][0], acc[tt][1]),
                                 fmaxf(acc[tt][2], acc[tt][3]));
                runmax[tt] = fmaxf(runmax[tt], m0);
            }
        } else {
            const int nb = nb0 + g * GRP;
            #pragma unroll
            for (int tt = 0; tt < 4; ++tt) {
                float m0 = fmaxf(fmaxf(acc[tt][0], acc[tt][1]),
                                 fmaxf(acc[tt][2], acc[tt][3]));
                if (m0 >= th[tt]) {
                    int g4 = (t0 + tt * 16 + lr) * 4 + h;
                    #pragma unroll
                    for (int r = 0; r < 4; ++r) {
                        if (acc[tt][r] >= th[tt]) {
                            int n = nb + lq * 4 + r;       // D row = lq*4+r
                            int pos = atomicAdd(&cnt[g4], 1);
                            if (pos < 64) {
                                float2 e; e.x = acc[tt][r]; e.y = __int_as_float(n);
                                buf[(size_t)g4 * 64 + pos] = e;
                            }
                        }
                    }
                }
            }
        }
        // stage group g+1 into the other buffer (safe: all waves passed the
        // barrier above, so nobody still reads buf[cb^1] from group g-1)
        if (g + 1 < NGRP) *(s16x8*)&Ks[cb ^ 1][srow][scol] = kst;
    }

    if (PASS == 1) {
        #pragma unroll
        for (int tt = 0; tt < 4; ++tt)
            maxbuf[(size_t)((t0 + tt * 16 + lr) * 4 + h) * 256 + sp * 4 + lq] = runmax[tt];
    }
}

// ---------------------------------------------------------------------------
// theta = 16th-largest of the 256 cell maxima per (t,h). The 256 cells
// partition all 25600 experts, so >=16 distinct experts score >= theta and
// every true top-16 score is >= theta.
// ---------------------------------------------------------------------------
__global__ __launch_bounds__(256) void theta_kernel(
        const float* __restrict__ maxbuf, float* __restrict__ theta) {
    int g = blockIdx.x * 256 + threadIdx.x;
    if (g >= 8192) return;
    const float* mb = maxbuf + (size_t)g * 256;
    float s[16];
    #pragma unroll
    for (int i = 0; i < 16; ++i) s[i] = NEG_INF;
    for (int j = 0; j < 256; ++j) {
        float v = mb[j];
        if (v > s[15]) {                 // sorted-desc shift insert
            #pragma unroll
            for (int i = 15; i > 0; --i)
                s[i] = (v > s[i - 1]) ? s[i - 1] : ((v > s[i]) ? v : s[i]);
            s[0] = (v > s[0]) ? v : s[0];
        }
    }
    theta[g] = s[15];
}

// ---------------------------------------------------------------------------
// Finalize: exact tie-aware top-16 of survivors (desc value, tie -> lower
// index, matching jax.lax.top_k), softmax gates, tiny SwiGLU 16->44->16,
// accumulate comb into per-token combsum. One thread per (token, head).
// ---------------------------------------------------------------------------
__global__ __launch_bounds__(256) void finalize_kernel(
        const int* __restrict__ cnt, const float2* __restrict__ buf,
        const float* __restrict__ sumx,
        const float* __restrict__ wdown, const float* __restrict__ wup,
        const float* __restrict__ aw1, const float* __restrict__ aw2,
        const float* __restrict__ aw3, float* __restrict__ combsum) {
    int g = blockIdx.x * 256 + threadIdx.x;    // (t*4 + h)
    if (g >= 8192) return;
    int t = g >> 2;
    int c = cnt[g]; c = (c > 64) ? 64 : c;
    float sv[16]; int si[16];
    #pragma unroll
    for (int i = 0; i < 16; ++i) { sv[i] = NEG_INF; si[i] = 0x7fffffff; }
    for (int j = 0; j < c; ++j) {
        float2 e = buf[(size_t)g * 64 + j];
        float v = e.x; int n = __float_as_int(e.y);
        bool beat = (v > sv[15]) || (v == sv[15] && n < si[15]);
        if (beat) {
            #pragma unroll
            for (int i = 15; i > 0; --i) {
                bool up  = (v > sv[i - 1]) || (v == sv[i - 1] && n < si[i - 1]);
                bool her = (v > sv[i])     || (v == sv[i]     && n < si[i]);
                float nv = up ? sv[i - 1] : (her ? v : sv[i]);
                int   ni = up ? si[i - 1] : (her ? n : si[i]);
                sv[i] = nv; si[i] = ni;
            }
            bool up0 = (v > sv[0]) || (v == sv[0] && n < si[0]);
            if (up0) { sv[0] = v; si[0] = n; }
        }
    }
    // softmax over sorted top-16 (max is sv[0])
    float mx = sv[0], den = 0.f;
    float gates[16];
    #pragma unroll
    for (int k = 0; k < 16; ++k) { gates[k] = expf(sv[k] - mx); den += gates[k]; }
    float rden = 1.f / den;
    float S = sumx[t];
    float z[16];
    #pragma unroll
    for (int k = 0; k < 16; ++k) z[k] = S * wdown[si[k]];
    float hk[16];
    #pragma unroll
    for (int k = 0; k < 16; ++k) hk[k] = 0.f;
    for (int j = 0; j < 44; ++j) {
        float u1 = 0.f, u3 = 0.f;
        #pragma unroll
        for (int k = 0; k < 16; ++k) {
            u1 += z[k] * aw1[j * 16 + k];
            u3 += z[k] * aw3[j * 16 + k];
        }
        float gj = u1 / (1.f + expf(-u1)) * u3;
        #pragma unroll
        for (int k = 0; k < 16; ++k) hk[k] += gj * aw2[k * 44 + j];
    }
    float comb = 0.f;
    #pragma unroll
    for (int k = 0; k < 16; ++k) comb += hk[k] * gates[k] * rden * wup[si[k]];
    atomicAdd(&combsum[t], comb);
}

// ---------------------------------------------------------------------------
// Host launch
// ---------------------------------------------------------------------------
extern "C" void kernel_launch(void* const* d_in, const int* in_sizes, int n_in,
                              void* d_out, int out_size, void* d_ws, size_t ws_size,
                              hipStream_t stream) {
    const float* x     = (const float*)d_in[0];
    const float* wq    = (const float*)d_in[1];
    const float* bq    = (const float*)d_in[2];
    const float* gamma = (const float*)d_in[3];
    const float* beta  = (const float*)d_in[4];
    const float* mean  = (const float*)d_in[5];
    const float* var   = (const float*)d_in[6];
    const float* keys  = (const float*)d_in[7];
    const float* wdown = (const float*)d_in[8];
    const float* wup   = (const float*)d_in[9];
    const float* aw1   = (const float*)d_in[10];
    const float* aw2   = (const float*)d_in[11];
    const float* aw3   = (const float*)d_in[12];
    const float* sw1   = (const float*)d_in[13];
    const float* sw2   = (const float*)d_in[14];
    const float* sw3   = (const float*)d_in[15];
    float* out = (float*)d_out;

    char* ws = (char*)d_ws;
    unsigned short* x_b    = (unsigned short*)(ws + 0);         // 3,145,728 B
    unsigned short* wq_b   = (unsigned short*)(ws + 3145728);   //   786,432
    unsigned short* sw1_b  = (unsigned short*)(ws + 3932160);   // 1,572,864
    unsigned short* sw3_b  = (unsigned short*)(ws + 5505024);   // 1,572,864
    unsigned short* sw2_b  = (unsigned short*)(ws + 7077888);   // 1,572,864
    unsigned short* keys_b = (unsigned short*)(ws + 8650752);   // 26,214,400
    unsigned short* q_b    = (unsigned short*)(ws + 34865152);  // 2,097,152
    float* sumx    = (float*)(ws + 36962304);                   //     8,192
    float* theta   = (float*)(ws + 36970496);                   //    32,768
    float* combsum = (float*)(ws + 37003264);                   //     8,192 } one
    int*   cnt     = (int*)  (ws + 37011456);                   //    32,768 } memset
    // R1 region (8 MB), sequentially reused:
    //   maxbuf (8 MB, pass1 -> theta) -> buf (4 MB, pass2 -> finalize)
    //   -> h_b (4 MB, swiglu -> down-GEMM)
    char* R1 = ws + 37044224;                                   // total ~45 MB
    float* maxbuf = (float*)R1;
    float2* buf   = (float2*)R1;
    unsigned short* h_b = (unsigned short*)R1;

    // one fused bf16 convert (x, wq, sw1, sw3, sw2, keys -> contiguous dst)
    cvt_all_kernel<<<17024, 256, 0, stream>>>(x, wq, sw1, sw3, sw2, keys, x_b);
    row_sum_kernel<<<512, 256, 0, stream>>>(x, sumx);
    hipMemsetAsync(combsum, 0, 40960, stream);   // combsum + cnt (adjacent)

    // q = BN(x @ wq^T + bq) -> bf16 (2048 x 512)
    gemm_nt<0><<<dim3(32, 8), 256, 0, stream>>>(x_b, wq_b, 2048, 512, 768,
                                                nullptr, q_b, bq, gamma, beta, mean, var);
    // pass 1: cell maxima (256 per (t,h))
    score_pass_kernel<1><<<2048, 256, 0, stream>>>(q_b, keys_b, maxbuf, nullptr, nullptr, nullptr);
    // theta = 16th-largest cell max
    theta_kernel<<<32, 256, 0, stream>>>(maxbuf, theta);
    // pass 2: recompute scores, compact survivors >= theta
    score_pass_kernel<2><<<2048, 256, 0, stream>>>(q_b, keys_b, nullptr, theta, cnt, buf);
    // exact top-16 + gates + tiny MLP -> combsum[t]
    finalize_kernel<<<32, 256, 0, stream>>>(cnt, buf, sumx, wdown, wup, aw1, aw2, aw3, combsum);
    // dense SwiGLU up (h bf16, 2048 x 1024)
    gemm_swiglu_kernel<<<dim3(32, 16), 256, 0, stream>>>(x_b, sw1_b, sw3_b, 2048, 1024, 768, h_b);
    // down-proj + combsum epilogue -> out fp32 (2048 x 768)
    gemm_nt<2><<<dim3(32, 12), 256, 0, stream>>>(h_b, sw2_b, 2048, 768, 1024,
                                                 out, nullptr, combsum,
                                                 nullptr, nullptr, nullptr, nullptr);
}

// Round 7
// 419.947 us; speedup vs baseline: 1.9439x; 1.9439x over previous
//
#include <hip/hip_runtime.h>
#include <hip/hip_bf16.h>
#include <cmath>

// ---------------------------------------------------------------------------
// Problem constants (B=1, T=2048, D=768, H=4, N=25600, KD=128, HQ=512,
// HID_A=44, HID_S=1024, KNN=16)
// ---------------------------------------------------------------------------
#define NEG_INF (-3.402823466e38f)
#define SPLITS 32          // N-splits per head
#define SPN    800         // experts per split
#define GRP    32          // experts per staged LDS group (2 MFMA A-tiles)
#define NGRP   25          // groups per split (800/32)

typedef __attribute__((ext_vector_type(8))) short s16x8;   // 8 bf16 (4 VGPRs)
typedef __attribute__((ext_vector_type(4))) float f32x4;   // MFMA C/D frag

__device__ __forceinline__ unsigned short f2bf(float f) {
    union { float f; unsigned u; } v; v.f = f;
    unsigned u = v.u;
    u += 0x7fffu + ((u >> 16) & 1u);   // round-to-nearest-even
    return (unsigned short)(u >> 16);
}

// ---------------------------------------------------------------------------
// One fused fp32->bf16 convert for ALL tensors: {x, wq, sw1, sw3, sw2} into
// ws[0..8650752) and keys into ws[8650752..34865152) (adjacent dst regions).
// Indexing in ushort4 (=float4-src) units.
// ---------------------------------------------------------------------------
__global__ __launch_bounds__(256) void cvt_all_kernel(
        const float* __restrict__ s0, const float* __restrict__ s1,
        const float* __restrict__ s2, const float* __restrict__ s3,
        const float* __restrict__ s4, const float* __restrict__ keys,
        unsigned short* __restrict__ dst) {
    int i = blockIdx.x * 256 + threadIdx.x;
    if (i >= 4358144) return;                      // 1081344 small + 3276800 keys
    const float* src; int base;
    if      (i < 393216)  { src = s0;   base = 0; }
    else if (i < 491520)  { src = s1;   base = 393216; }
    else if (i < 688128)  { src = s2;   base = 491520; }
    else if (i < 884736)  { src = s3;   base = 688128; }
    else if (i < 1081344) { src = s4;   base = 884736; }
    else                  { src = keys; base = 1081344; }
    float4 f = ((const float4*)src)[i - base];
    ushort4 o;
    o.x = f2bf(f.x); o.y = f2bf(f.y); o.z = f2bf(f.z); o.w = f2bf(f.w);
    ((ushort4*)dst)[i] = o;
}

// ---------------------------------------------------------------------------
// per-token row sum of x (fp32), one wave per token
// ---------------------------------------------------------------------------
__global__ __launch_bounds__(256) void row_sum_kernel(
        const float* __restrict__ x, float* __restrict__ sumx) {
    int gw = (blockIdx.x * 256 + threadIdx.x) >> 6;   // token id (grid sized exact)
    int lane = threadIdx.x & 63;
    const float* row = x + (size_t)gw * 768;
    float s = 0.f;
    #pragma unroll
    for (int k = 0; k < 12; ++k) s += row[lane + k * 64];
    #pragma unroll
    for (int off = 32; off > 0; off >>= 1) s += __shfl_down(s, off);
    if (lane == 0) sumx[gw] = s;
}

// ---------------------------------------------------------------------------
// GEMM  C = A @ W^T  (A: MxK bf16 row-major, W: NxK bf16 row-major)
// 64x64 tile, BK=64, 256 threads (4 waves in 2x2), 16x16x32 bf16 MFMA.
// EPI 0: q-projection epilogue (+bq, BatchNorm) -> bf16 outB
// EPI 2: final epilogue (+combsum[m]) -> fp32 outF
// ---------------------------------------------------------------------------
template <int EPI>
__global__ __launch_bounds__(256) void gemm_nt(
        const unsigned short* __restrict__ A, const unsigned short* __restrict__ W,
        int M, int N, int K,
        float* __restrict__ outF, unsigned short* __restrict__ outB,
        const float* __restrict__ p0, const float* __restrict__ p1,
        const float* __restrict__ p2, const float* __restrict__ p3,
        const float* __restrict__ p4) {
    __shared__ alignas(16) short As[64][72];   // +8 bf16 pad: 144B stride, 16B-aligned rows
    __shared__ alignas(16) short Ws[64][72];
    const int tid = threadIdx.x;
    const int m0 = blockIdx.x * 64, n0 = blockIdx.y * 64;
    const int wv = tid >> 6, lane = tid & 63;
    const int wr = wv >> 1, wc = wv & 1;
    const int lr = lane & 15, lq = lane >> 4;
    f32x4 acc[2][2];
    #pragma unroll
    for (int i = 0; i < 2; ++i)
        #pragma unroll
        for (int j = 0; j < 2; ++j) acc[i][j] = (f32x4){0.f, 0.f, 0.f, 0.f};

    for (int kb = 0; kb < K; kb += 64) {
        #pragma unroll
        for (int it = 0; it < 2; ++it) {            // 512 chunks of 8 bf16
            int chunk = tid + it * 256;
            int row = chunk >> 3, c8 = (chunk & 7) * 8;
            *(s16x8*)&As[row][c8] = *(const s16x8*)(A + (size_t)(m0 + row) * K + kb + c8);
            *(s16x8*)&Ws[row][c8] = *(const s16x8*)(W + (size_t)(n0 + row) * K + kb + c8);
        }
        __syncthreads();
        #pragma unroll
        for (int ks = 0; ks < 2; ++ks) {
            const int k0 = ks * 32 + lq * 8;
            #pragma unroll
            for (int rt = 0; rt < 2; ++rt) {
                s16x8 a = *(const s16x8*)&As[wr * 32 + rt * 16 + lr][k0];
                #pragma unroll
                for (int ct = 0; ct < 2; ++ct) {
                    s16x8 b = *(const s16x8*)&Ws[wc * 32 + ct * 16 + lr][k0];
                    acc[rt][ct] = __builtin_amdgcn_mfma_f32_16x16x32_bf16(a, b, acc[rt][ct], 0, 0, 0);
                }
            }
        }
        __syncthreads();
    }
    // C/D layout: col = lane&15, row = (lane>>4)*4 + r  [verified m89/m91]
    #pragma unroll
    for (int rt = 0; rt < 2; ++rt)
        #pragma unroll
        for (int ct = 0; ct < 2; ++ct)
            #pragma unroll
            for (int r = 0; r < 4; ++r) {
                int m = m0 + wr * 32 + rt * 16 + lq * 4 + r;
                int n = n0 + wc * 32 + ct * 16 + lr;
                float v = acc[rt][ct][r];
                if (EPI == 0) {
                    float q = v + p0[n];
                    q = (q - p3[n]) * rsqrtf(p4[n] + 1e-5f) * p1[n] + p2[n];
                    outB[(size_t)m * N + n] = f2bf(q);
                } else {
                    outF[(size_t)m * N + n] = v + p0[m];
                }
            }
}

// ---------------------------------------------------------------------------
// Dense SwiGLU up: h = silu(x@W1^T) * (x@W3^T) -> bf16, dual accumulators
// ---------------------------------------------------------------------------
__global__ __launch_bounds__(256) void gemm_swiglu_kernel(
        const unsigned short* __restrict__ A, const unsigned short* __restrict__ W1,
        const unsigned short* __restrict__ W3, int M, int N, int K,
        unsigned short* __restrict__ outB) {
    __shared__ alignas(16) short As[64][72];
    __shared__ alignas(16) short W1s[64][72];
    __shared__ alignas(16) short W3s[64][72];
    const int tid = threadIdx.x;
    const int m0 = blockIdx.x * 64, n0 = blockIdx.y * 64;
    const int wv = tid >> 6, lane = tid & 63;
    const int wr = wv >> 1, wc = wv & 1;
    const int lr = lane & 15, lq = lane >> 4;
    f32x4 acc1[2][2], acc3[2][2];
    #pragma unroll
    for (int i = 0; i < 2; ++i)
        #pragma unroll
        for (int j = 0; j < 2; ++j) {
            acc1[i][j] = (f32x4){0.f, 0.f, 0.f, 0.f};
            acc3[i][j] = (f32x4){0.f, 0.f, 0.f, 0.f};
        }
    for (int kb = 0; kb < K; kb += 64) {
        #pragma unroll
        for (int it = 0; it < 2; ++it) {
            int chunk = tid + it * 256;
            int row = chunk >> 3, c8 = (chunk & 7) * 8;
            *(s16x8*)&As[row][c8]  = *(const s16x8*)(A  + (size_t)(m0 + row) * K + kb + c8);
            *(s16x8*)&W1s[row][c8] = *(const s16x8*)(W1 + (size_t)(n0 + row) * K + kb + c8);
            *(s16x8*)&W3s[row][c8] = *(const s16x8*)(W3 + (size_t)(n0 + row) * K + kb + c8);
        }
        __syncthreads();
        #pragma unroll
        for (int ks = 0; ks < 2; ++ks) {
            const int k0 = ks * 32 + lq * 8;
            #pragma unroll
            for (int rt = 0; rt < 2; ++rt) {
                s16x8 a = *(const s16x8*)&As[wr * 32 + rt * 16 + lr][k0];
                #pragma unroll
                for (int ct = 0; ct < 2; ++ct) {
                    s16x8 b1 = *(const s16x8*)&W1s[wc * 32 + ct * 16 + lr][k0];
                    s16x8 b3 = *(const s16x8*)&W3s[wc * 32 + ct * 16 + lr][k0];
                    acc1[rt][ct] = __builtin_amdgcn_mfma_f32_16x16x32_bf16(a, b1, acc1[rt][ct], 0, 0, 0);
                    acc3[rt][ct] = __builtin_amdgcn_mfma_f32_16x16x32_bf16(a, b3, acc3[rt][ct], 0, 0, 0);
                }
            }
        }
        __syncthreads();
    }
    #pragma unroll
    for (int rt = 0; rt < 2; ++rt)
        #pragma unroll
        for (int ct = 0; ct < 2; ++ct)
            #pragma unroll
            for (int r = 0; r < 4; ++r) {
                int m = m0 + wr * 32 + rt * 16 + lq * 4 + r;
                int n = n0 + wc * 32 + ct * 16 + lr;
                float u1 = acc1[rt][ct][r], u3 = acc3[rt][ct][r];
                float hv = u1 / (1.f + expf(-u1)) * u3;
                outB[(size_t)m * N + n] = f2bf(hv);
            }
}

// ---------------------------------------------------------------------------
// Score pass kernel (both passes share the body -> bitwise-identical scores).
// A = K (experts = rows), B = Q (tokens = cols): each lane's 4 acc values
// belong to ONE token. Q register-resident.
//
// Round-7: EXACT round-4 code shape (GRP=32, SPLITS=32, grid 1024, 17.4 KB
// double-buffered LDS, two 16-expert subtiles per group, launch_bounds
// (256,4)) -- that shape is proven NO-SPILL under the 128-reg budget (r4:
// VGPR=64+acc, WRITE 11 MB). r6's GRP=16 shape hit a register-allocation
// cliff: the allocator spilled loop state to scratch (WRITE_SIZE 715 MB/pass,
// 4x slowdown). Only change vs r4: keys are PRE-CONVERTED bf16, so staging
// is two 16B loads + two ds_write_b128 (no f2bf VALU in the hot loop, half
// the staged/L2 bytes of r4).
//
// PASS 1: per-(lane,token) running max -> maxbuf (128 disjoint cell-maxima
//         per (t,h): cell = (sp, lq), 25 groups x 2 subtiles x 4 rows).
// PASS 2: recompute scores, keep (v,idx) with v >= theta[t,h] via atomic
//         compaction (expected ~17-20 survivors, cap 64).
// ---------------------------------------------------------------------------
template <int PASS>
__global__ __launch_bounds__(256, 4) void score_pass_kernel(
        const unsigned short* __restrict__ Q,    // 2048 x 512 bf16
        const unsigned short* __restrict__ Kt,   // 4 x 25600 x 128 bf16
        float* __restrict__ maxbuf,              // [8192][128]  (pass 1 out)
        const float* __restrict__ theta,         // [8192]       (pass 2 in)
        int* __restrict__ cnt,                   // [8192]       (pass 2)
        float2* __restrict__ buf) {              // [8192][64]   (pass 2 out)
    __shared__ alignas(16) short Ks[2][GRP][136];   // 2 x 32 x 272B = 17.4 KB
    const int b = blockIdx.x;
    const int tile = b >> 7;                     // 128 = 4 heads x 32 splits
    const int hsp = b & 127;
    const int h = hsp >> 5, sp = hsp & 31;
    const int w = threadIdx.x >> 6, lane = threadIdx.x & 63;
    const int lr = lane & 15, lq = lane >> 4;
    const int t0 = tile * 256 + w * 64;
    const int nb0 = sp * SPN;

    // Q fragments: 4 token-tiles x 4 k-steps, register-resident
    s16x8 qf[4][4];
    #pragma unroll
    for (int tt = 0; tt < 4; ++tt) {
        const unsigned short* qp = Q + (size_t)(t0 + tt * 16 + lr) * 512 + h * 128 + lq * 8;
        #pragma unroll
        for (int ks = 0; ks < 4; ++ks) qf[tt][ks] = *(const s16x8*)(qp + ks * 32);
    }

    float runmax[4] = {NEG_INF, NEG_INF, NEG_INF, NEG_INF};
    float th[4];
    if (PASS == 2) {
        #pragma unroll
        for (int tt = 0; tt < 4; ++tt) th[tt] = theta[(t0 + tt * 16 + lr) * 4 + h];
    }

    // Staging: thread (srow, scol) covers rows srow / srow+16 of each 32-row
    // group, one 16B bf16 chunk each -> coalesced loads, ds_write_b128.
    const int srow = threadIdx.x >> 4;           // 0..15
    const int scol = (threadIdx.x & 15) * 8;     // bf16 elem 0..120
    const unsigned short* kgp =
        Kt + ((size_t)h * 25600 + nb0 + srow) * 128 + scol;
    // group stride = 32 rows * 128 = 4096 bf16; subtile stride = 2048.

    {   // prologue: stage group 0 into buffer 0
        *(s16x8*)&Ks[0][srow][scol]      = *(const s16x8*)kgp;
        *(s16x8*)&Ks[0][srow + 16][scol] = *(const s16x8*)(kgp + 2048);
    }

    for (int g = 0; g < NGRP; ++g) {
        // issue global loads for group g+1 (consumed after this group's MFMAs)
        s16x8 ka0, ka1;
        if (g + 1 < NGRP) {
            const unsigned short* kp = kgp + (size_t)(g + 1) * 4096;
            ka0 = *(const s16x8*)kp;
            ka1 = *(const s16x8*)(kp + 2048);
        }
        __syncthreads();                          // buf[g&1] ready for all waves
        const int cb = g & 1;
        #pragma unroll
        for (int st = 0; st < 2; ++st) {          // 2 expert subtiles of 16
            f32x4 acc[4];
            #pragma unroll
            for (int tt = 0; tt < 4; ++tt) acc[tt] = (f32x4){0.f, 0.f, 0.f, 0.f};
            #pragma unroll
            for (int ks = 0; ks < 4; ++ks) {
                s16x8 ka = *(const s16x8*)&Ks[cb][st * 16 + lr][ks * 32 + lq * 8];
                #pragma unroll
                for (int tt = 0; tt < 4; ++tt)
                    acc[tt] = __builtin_amdgcn_mfma_f32_16x16x32_bf16(ka, qf[tt][ks], acc[tt], 0, 0, 0);
            }
            if (PASS == 1) {
                #pragma unroll
                for (int tt = 0; tt < 4; ++tt) {
                    float m0 = fmaxf(fmaxf(acc[tt][0], acc[tt][1]),
                                     fmaxf(acc[tt][2], acc[tt][3]));
                    runmax[tt] = fmaxf(runmax[tt], m0);
                }
            } else {
                const int nb = nb0 + g * GRP + st * 16;
                #pragma unroll
                for (int tt = 0; tt < 4; ++tt) {
                    float m0 = fmaxf(fmaxf(acc[tt][0], acc[tt][1]),
                                     fmaxf(acc[tt][2], acc[tt][3]));
                    if (m0 >= th[tt]) {
                        int g4 = (t0 + tt * 16 + lr) * 4 + h;
                        #pragma unroll
                        for (int r = 0; r < 4; ++r) {
                            if (acc[tt][r] >= th[tt]) {
                                int n = nb + lq * 4 + r;   // D row = lq*4+r
                                int pos = atomicAdd(&cnt[g4], 1);
                                if (pos < 64) {
                                    float2 e; e.x = acc[tt][r]; e.y = __int_as_float(n);
                                    buf[(size_t)g4 * 64 + pos] = e;
                                }
                            }
                        }
                    }
                }
            }
        }
        // stage group g+1 into the other buffer (vmcnt wait lands here,
        // after this group's MFMAs have issued)
        if (g + 1 < NGRP) {
            const int nbuf = cb ^ 1;
            *(s16x8*)&Ks[nbuf][srow][scol]      = ka0;
            *(s16x8*)&Ks[nbuf][srow + 16][scol] = ka1;
        }
    }

    if (PASS == 1) {
        #pragma unroll
        for (int tt = 0; tt < 4; ++tt)
            maxbuf[(size_t)((t0 + tt * 16 + lr) * 4 + h) * 128 + sp * 4 + lq] = runmax[tt];
    }
}

// ---------------------------------------------------------------------------
// theta = 16th-largest of the 128 cell maxima per (t,h). The 128 cells
// partition all 25600 experts, so >=16 distinct experts score >= theta and
// every true top-16 score is >= theta.
// ---------------------------------------------------------------------------
__global__ __launch_bounds__(256) void theta_kernel(
        const float* __restrict__ maxbuf, float* __restrict__ theta) {
    int g = blockIdx.x * 256 + threadIdx.x;
    if (g >= 8192) return;
    const float* mb = maxbuf + (size_t)g * 128;
    float s[16];
    #pragma unroll
    for (int i = 0; i < 16; ++i) s[i] = NEG_INF;
    for (int j = 0; j < 128; ++j) {
        float v = mb[j];
        if (v > s[15]) {                 // sorted-desc shift insert
            #pragma unroll
            for (int i = 15; i > 0; --i)
                s[i] = (v > s[i - 1]) ? s[i - 1] : ((v > s[i]) ? v : s[i]);
            s[0] = (v > s[0]) ? v : s[0];
        }
    }
    theta[g] = s[15];
}

// ---------------------------------------------------------------------------
// Finalize: exact tie-aware top-16 of survivors (desc value, tie -> lower
// index, matching jax.lax.top_k), softmax gates, tiny SwiGLU 16->44->16,
// accumulate comb into per-token combsum. One thread per (token, head).
// ---------------------------------------------------------------------------
__global__ __launch_bounds__(256) void finalize_kernel(
        const int* __restrict__ cnt, const float2* __restrict__ buf,
        const float* __restrict__ sumx,
        const float* __restrict__ wdown, const float* __restrict__ wup,
        const float* __restrict__ aw1, const float* __restrict__ aw2,
        const float* __restrict__ aw3, float* __restrict__ combsum) {
    int g = blockIdx.x * 256 + threadIdx.x;    // (t*4 + h)
    if (g >= 8192) return;
    int t = g >> 2;
    int c = cnt[g]; c = (c > 64) ? 64 : c;
    float sv[16]; int si[16];
    #pragma unroll
    for (int i = 0; i < 16; ++i) { sv[i] = NEG_INF; si[i] = 0x7fffffff; }
    for (int j = 0; j < c; ++j) {
        float2 e = buf[(size_t)g * 64 + j];
        float v = e.x; int n = __float_as_int(e.y);
        bool beat = (v > sv[15]) || (v == sv[15] && n < si[15]);
        if (beat) {
            #pragma unroll
            for (int i = 15; i > 0; --i) {
                bool up  = (v > sv[i - 1]) || (v == sv[i - 1] && n < si[i - 1]);
                bool her = (v > sv[i])     || (v == sv[i]     && n < si[i]);
                float nv = up ? sv[i - 1] : (her ? v : sv[i]);
                int   ni = up ? si[i - 1] : (her ? n : si[i]);
                sv[i] = nv; si[i] = ni;
            }
            bool up0 = (v > sv[0]) || (v == sv[0] && n < si[0]);
            if (up0) { sv[0] = v; si[0] = n; }
        }
    }
    // softmax over sorted top-16 (max is sv[0])
    float mx = sv[0], den = 0.f;
    float gates[16];
    #pragma unroll
    for (int k = 0; k < 16; ++k) { gates[k] = expf(sv[k] - mx); den += gates[k]; }
    float rden = 1.f / den;
    float S = sumx[t];
    float z[16];
    #pragma unroll
    for (int k = 0; k < 16; ++k) z[k] = S * wdown[si[k]];
    float hk[16];
    #pragma unroll
    for (int k = 0; k < 16; ++k) hk[k] = 0.f;
    for (int j = 0; j < 44; ++j) {
        float u1 = 0.f, u3 = 0.f;
        #pragma unroll
        for (int k = 0; k < 16; ++k) {
            u1 += z[k] * aw1[j * 16 + k];
            u3 += z[k] * aw3[j * 16 + k];
        }
        float gj = u1 / (1.f + expf(-u1)) * u3;
        #pragma unroll
        for (int k = 0; k < 16; ++k) hk[k] += gj * aw2[k * 44 + j];
    }
    float comb = 0.f;
    #pragma unroll
    for (int k = 0; k < 16; ++k) comb += hk[k] * gates[k] * rden * wup[si[k]];
    atomicAdd(&combsum[t], comb);
}

// ---------------------------------------------------------------------------
// Host launch
// ---------------------------------------------------------------------------
extern "C" void kernel_launch(void* const* d_in, const int* in_sizes, int n_in,
                              void* d_out, int out_size, void* d_ws, size_t ws_size,
                              hipStream_t stream) {
    const float* x     = (const float*)d_in[0];
    const float* wq    = (const float*)d_in[1];
    const float* bq    = (const float*)d_in[2];
    const float* gamma = (const float*)d_in[3];
    const float* beta  = (const float*)d_in[4];
    const float* mean  = (const float*)d_in[5];
    const float* var   = (const float*)d_in[6];
    const float* keys  = (const float*)d_in[7];
    const float* wdown = (const float*)d_in[8];
    const float* wup   = (const float*)d_in[9];
    const float* aw1   = (const float*)d_in[10];
    const float* aw2   = (const float*)d_in[11];
    const float* aw3   = (const float*)d_in[12];
    const float* sw1   = (const float*)d_in[13];
    const float* sw2   = (const float*)d_in[14];
    const float* sw3   = (const float*)d_in[15];
    float* out = (float*)d_out;

    char* ws = (char*)d_ws;
    unsigned short* x_b    = (unsigned short*)(ws + 0);         // 3,145,728 B
    unsigned short* wq_b   = (unsigned short*)(ws + 3145728);   //   786,432
    unsigned short* sw1_b  = (unsigned short*)(ws + 3932160);   // 1,572,864
    unsigned short* sw3_b  = (unsigned short*)(ws + 5505024);   // 1,572,864
    unsigned short* sw2_b  = (unsigned short*)(ws + 7077888);   // 1,572,864
    unsigned short* keys_b = (unsigned short*)(ws + 8650752);   // 26,214,400
    unsigned short* q_b    = (unsigned short*)(ws + 34865152);  // 2,097,152
    float* sumx    = (float*)(ws + 36962304);                   //     8,192
    float* theta   = (float*)(ws + 36970496);                   //    32,768
    float* combsum = (float*)(ws + 37003264);                   //     8,192 } one
    int*   cnt     = (int*)  (ws + 37011456);                   //    32,768 } memset
    // R1 region (4 MB), sequentially reused:
    //   maxbuf (4 MB, pass1 -> theta) -> buf (4 MB, pass2 -> finalize)
    //   -> h_b (4 MB, swiglu -> down-GEMM)
    char* R1 = ws + 37044224;                                   // total ~41 MB
    float* maxbuf = (float*)R1;
    float2* buf   = (float2*)R1;
    unsigned short* h_b = (unsigned short*)R1;

    // one fused bf16 convert (x, wq, sw1, sw3, sw2, keys -> contiguous dst)
    cvt_all_kernel<<<17024, 256, 0, stream>>>(x, wq, sw1, sw3, sw2, keys, x_b);
    row_sum_kernel<<<512, 256, 0, stream>>>(x, sumx);
    hipMemsetAsync(combsum, 0, 40960, stream);   // combsum + cnt (adjacent)

    // q = BN(x @ wq^T + bq) -> bf16 (2048 x 512)
    gemm_nt<0><<<dim3(32, 8), 256, 0, stream>>>(x_b, wq_b, 2048, 512, 768,
                                                nullptr, q_b, bq, gamma, beta, mean, var);
    // pass 1: cell maxima (128 per (t,h))
    score_pass_kernel<1><<<1024, 256, 0, stream>>>(q_b, keys_b, maxbuf, nullptr, nullptr, nullptr);
    // theta = 16th-largest cell max
    theta_kernel<<<32, 256, 0, stream>>>(maxbuf, theta);
    // pass 2: recompute scores, compact survivors >= theta
    score_pass_kernel<2><<<1024, 256, 0, stream>>>(q_b, keys_b, nullptr, theta, cnt, buf);
    // exact top-16 + gates + tiny MLP -> combsum[t]
    finalize_kernel<<<32, 256, 0, stream>>>(cnt, buf, sumx, wdown, wup, aw1, aw2, aw3, combsum);
    // dense SwiGLU up (h bf16, 2048 x 1024)
    gemm_swiglu_kernel<<<dim3(32, 16), 256, 0, stream>>>(x_b, sw1_b, sw3_b, 2048, 1024, 768, h_b);
    // down-proj + combsum epilogue -> out fp32 (2048 x 768)
    gemm_nt<2><<<dim3(32, 12), 256, 0, stream>>>(h_b, sw2_b, 2048, 768, 1024,
                                                 out, nullptr, combsum,
                                                 nullptr, nullptr, nullptr, nullptr);
}

// Round 8
// 354.677 us; speedup vs baseline: 2.3016x; 1.1840x over previous
//
#include <hip/hip_runtime.h>
#include <hip/hip_bf16.h>
#include <cmath>

// ---------------------------------------------------------------------------
// Problem constants (B=1, T=2048, D=768, H=4, N=25600, KD=128, HQ=512,
// HID_A=44, HID_S=1024, KNN=16)
// ---------------------------------------------------------------------------
#define NEG_INF (-3.402823466e38f)
#define SPLITS 32          // N-splits per head
#define SPN    800         // experts per split
#define GRP    32          // experts per staged LDS group (2 MFMA A-tiles)
#define NGRP   25          // groups per split (800/32)

typedef __attribute__((ext_vector_type(8))) short s16x8;   // 8 bf16 (4 VGPRs)
typedef __attribute__((ext_vector_type(4))) float f32x4;   // MFMA C/D frag

__device__ __forceinline__ unsigned short f2bf(float f) {
    union { float f; unsigned u; } v; v.f = f;
    unsigned u = v.u;
    u += 0x7fffu + ((u >> 16) & 1u);   // round-to-nearest-even
    return (unsigned short)(u >> 16);
}

// ---------------------------------------------------------------------------
// One fused fp32->bf16 convert for ALL tensors: {x, wq, sw1, sw3, sw2} into
// ws[0..8650752) and keys into ws[8650752..34865152) (adjacent dst regions).
// Indexing in ushort4 (=float4-src) units.
// ---------------------------------------------------------------------------
__global__ __launch_bounds__(256) void cvt_all_kernel(
        const float* __restrict__ s0, const float* __restrict__ s1,
        const float* __restrict__ s2, const float* __restrict__ s3,
        const float* __restrict__ s4, const float* __restrict__ keys,
        unsigned short* __restrict__ dst) {
    int i = blockIdx.x * 256 + threadIdx.x;
    if (i >= 4358144) return;                      // 1081344 small + 3276800 keys
    const float* src; int base;
    if      (i < 393216)  { src = s0;   base = 0; }
    else if (i < 491520)  { src = s1;   base = 393216; }
    else if (i < 688128)  { src = s2;   base = 491520; }
    else if (i < 884736)  { src = s3;   base = 688128; }
    else if (i < 1081344) { src = s4;   base = 884736; }
    else                  { src = keys; base = 1081344; }
    float4 f = ((const float4*)src)[i - base];
    ushort4 o;
    o.x = f2bf(f.x); o.y = f2bf(f.y); o.z = f2bf(f.z); o.w = f2bf(f.w);
    ((ushort4*)dst)[i] = o;
}

// ---------------------------------------------------------------------------
// per-token row sum of x (fp32), one wave per token
// ---------------------------------------------------------------------------
__global__ __launch_bounds__(256) void row_sum_kernel(
        const float* __restrict__ x, float* __restrict__ sumx) {
    int gw = (blockIdx.x * 256 + threadIdx.x) >> 6;   // token id (grid sized exact)
    int lane = threadIdx.x & 63;
    const float* row = x + (size_t)gw * 768;
    float s = 0.f;
    #pragma unroll
    for (int k = 0; k < 12; ++k) s += row[lane + k * 64];
    #pragma unroll
    for (int off = 32; off > 0; off >>= 1) s += __shfl_down(s, off);
    if (lane == 0) sumx[gw] = s;
}

// ---------------------------------------------------------------------------
// GEMM  C = A @ W^T  (A: MxK bf16 row-major, W: NxK bf16 row-major)
// 64x64 tile, BK=64, 256 threads (4 waves in 2x2), 16x16x32 bf16 MFMA.
// EPI 0: q-projection epilogue (+bq, BatchNorm) -> bf16 outB
// EPI 2: final epilogue (+combsum[m]) -> fp32 outF
// ---------------------------------------------------------------------------
template <int EPI>
__global__ __launch_bounds__(256) void gemm_nt(
        const unsigned short* __restrict__ A, const unsigned short* __restrict__ W,
        int M, int N, int K,
        float* __restrict__ outF, unsigned short* __restrict__ outB,
        const float* __restrict__ p0, const float* __restrict__ p1,
        const float* __restrict__ p2, const float* __restrict__ p3,
        const float* __restrict__ p4) {
    __shared__ alignas(16) short As[64][72];   // +8 bf16 pad: 144B stride, 16B-aligned rows
    __shared__ alignas(16) short Ws[64][72];
    const int tid = threadIdx.x;
    const int m0 = blockIdx.x * 64, n0 = blockIdx.y * 64;
    const int wv = tid >> 6, lane = tid & 63;
    const int wr = wv >> 1, wc = wv & 1;
    const int lr = lane & 15, lq = lane >> 4;
    f32x4 acc[2][2];
    #pragma unroll
    for (int i = 0; i < 2; ++i)
        #pragma unroll
        for (int j = 0; j < 2; ++j) acc[i][j] = (f32x4){0.f, 0.f, 0.f, 0.f};

    for (int kb = 0; kb < K; kb += 64) {
        #pragma unroll
        for (int it = 0; it < 2; ++it) {            // 512 chunks of 8 bf16
            int chunk = tid + it * 256;
            int row = chunk >> 3, c8 = (chunk & 7) * 8;
            *(s16x8*)&As[row][c8] = *(const s16x8*)(A + (size_t)(m0 + row) * K + kb + c8);
            *(s16x8*)&Ws[row][c8] = *(const s16x8*)(W + (size_t)(n0 + row) * K + kb + c8);
        }
        __syncthreads();
        #pragma unroll
        for (int ks = 0; ks < 2; ++ks) {
            const int k0 = ks * 32 + lq * 8;
            #pragma unroll
            for (int rt = 0; rt < 2; ++rt) {
                s16x8 a = *(const s16x8*)&As[wr * 32 + rt * 16 + lr][k0];
                #pragma unroll
                for (int ct = 0; ct < 2; ++ct) {
                    s16x8 b = *(const s16x8*)&Ws[wc * 32 + ct * 16 + lr][k0];
                    acc[rt][ct] = __builtin_amdgcn_mfma_f32_16x16x32_bf16(a, b, acc[rt][ct], 0, 0, 0);
                }
            }
        }
        __syncthreads();
    }
    // C/D layout: col = lane&15, row = (lane>>4)*4 + r  [verified m89/m91]
    #pragma unroll
    for (int rt = 0; rt < 2; ++rt)
        #pragma unroll
        for (int ct = 0; ct < 2; ++ct)
            #pragma unroll
            for (int r = 0; r < 4; ++r) {
                int m = m0 + wr * 32 + rt * 16 + lq * 4 + r;
                int n = n0 + wc * 32 + ct * 16 + lr;
                float v = acc[rt][ct][r];
                if (EPI == 0) {
                    float q = v + p0[n];
                    q = (q - p3[n]) * rsqrtf(p4[n] + 1e-5f) * p1[n] + p2[n];
                    outB[(size_t)m * N + n] = f2bf(q);
                } else {
                    outF[(size_t)m * N + n] = v + p0[m];
                }
            }
}

// ---------------------------------------------------------------------------
// Dense SwiGLU up: h = silu(x@W1^T) * (x@W3^T) -> bf16, dual accumulators
// ---------------------------------------------------------------------------
__global__ __launch_bounds__(256) void gemm_swiglu_kernel(
        const unsigned short* __restrict__ A, const unsigned short* __restrict__ W1,
        const unsigned short* __restrict__ W3, int M, int N, int K,
        unsigned short* __restrict__ outB) {
    __shared__ alignas(16) short As[64][72];
    __shared__ alignas(16) short W1s[64][72];
    __shared__ alignas(16) short W3s[64][72];
    const int tid = threadIdx.x;
    const int m0 = blockIdx.x * 64, n0 = blockIdx.y * 64;
    const int wv = tid >> 6, lane = tid & 63;
    const int wr = wv >> 1, wc = wv & 1;
    const int lr = lane & 15, lq = lane >> 4;
    f32x4 acc1[2][2], acc3[2][2];
    #pragma unroll
    for (int i = 0; i < 2; ++i)
        #pragma unroll
        for (int j = 0; j < 2; ++j) {
            acc1[i][j] = (f32x4){0.f, 0.f, 0.f, 0.f};
            acc3[i][j] = (f32x4){0.f, 0.f, 0.f, 0.f};
        }
    for (int kb = 0; kb < K; kb += 64) {
        #pragma unroll
        for (int it = 0; it < 2; ++it) {
            int chunk = tid + it * 256;
            int row = chunk >> 3, c8 = (chunk & 7) * 8;
            *(s16x8*)&As[row][c8]  = *(const s16x8*)(A  + (size_t)(m0 + row) * K + kb + c8);
            *(s16x8*)&W1s[row][c8] = *(const s16x8*)(W1 + (size_t)(n0 + row) * K + kb + c8);
            *(s16x8*)&W3s[row][c8] = *(const s16x8*)(W3 + (size_t)(n0 + row) * K + kb + c8);
        }
        __syncthreads();
        #pragma unroll
        for (int ks = 0; ks < 2; ++ks) {
            const int k0 = ks * 32 + lq * 8;
            #pragma unroll
            for (int rt = 0; rt < 2; ++rt) {
                s16x8 a = *(const s16x8*)&As[wr * 32 + rt * 16 + lr][k0];
                #pragma unroll
                for (int ct = 0; ct < 2; ++ct) {
                    s16x8 b1 = *(const s16x8*)&W1s[wc * 32 + ct * 16 + lr][k0];
                    s16x8 b3 = *(const s16x8*)&W3s[wc * 32 + ct * 16 + lr][k0];
                    acc1[rt][ct] = __builtin_amdgcn_mfma_f32_16x16x32_bf16(a, b1, acc1[rt][ct], 0, 0, 0);
                    acc3[rt][ct] = __builtin_amdgcn_mfma_f32_16x16x32_bf16(a, b3, acc3[rt][ct], 0, 0, 0);
                }
            }
        }
        __syncthreads();
    }
    #pragma unroll
    for (int rt = 0; rt < 2; ++rt)
        #pragma unroll
        for (int ct = 0; ct < 2; ++ct)
            #pragma unroll
            for (int r = 0; r < 4; ++r) {
                int m = m0 + wr * 32 + rt * 16 + lq * 4 + r;
                int n = n0 + wc * 32 + ct * 16 + lr;
                float u1 = acc1[rt][ct][r], u3 = acc3[rt][ct][r];
                float hv = u1 / (1.f + expf(-u1)) * u3;
                outB[(size_t)m * N + n] = f2bf(hv);
            }
}

// ---------------------------------------------------------------------------
// Score pass kernel (both passes share the body -> bitwise-identical scores).
// A = K (experts = rows), B = Q (tokens = cols): each lane's 4 acc values
// belong to ONE token. Q register-resident.
//
// GRP=32 / two-subtile shape is LOAD-BEARING (no-spill under (256,4); the
// GRP=16 shape spilled 715 MB/pass — r6). Keys pre-converted bf16.
//
// PASS 1: per-(lane,token) running max -> maxbuf (128 disjoint cell-maxima
//         per (t,h): cell = (sp, lq), 25 groups x 2 subtiles x 4 rows).
// PASS 2: recompute scores, keep (v,idx) with v >= theta[t,h] via atomic
//         compaction (expected ~17-20 survivors, cap 64).
// ---------------------------------------------------------------------------
template <int PASS>
__global__ __launch_bounds__(256, 4) void score_pass_kernel(
        const unsigned short* __restrict__ Q,    // 2048 x 512 bf16
        const unsigned short* __restrict__ Kt,   // 4 x 25600 x 128 bf16
        float* __restrict__ maxbuf,              // [8192][128]  (pass 1 out)
        const float* __restrict__ theta,         // [8192]       (pass 2 in)
        int* __restrict__ cnt,                   // [8192]       (pass 2)
        float2* __restrict__ buf) {              // [8192][64]   (pass 2 out)
    __shared__ alignas(16) short Ks[2][GRP][136];   // 2 x 32 x 272B = 17.4 KB
    const int b = blockIdx.x;
    const int tile = b >> 7;                     // 128 = 4 heads x 32 splits
    const int hsp = b & 127;
    const int h = hsp >> 5, sp = hsp & 31;
    const int w = threadIdx.x >> 6, lane = threadIdx.x & 63;
    const int lr = lane & 15, lq = lane >> 4;
    const int t0 = tile * 256 + w * 64;
    const int nb0 = sp * SPN;

    // Q fragments: 4 token-tiles x 4 k-steps, register-resident
    s16x8 qf[4][4];
    #pragma unroll
    for (int tt = 0; tt < 4; ++tt) {
        const unsigned short* qp = Q + (size_t)(t0 + tt * 16 + lr) * 512 + h * 128 + lq * 8;
        #pragma unroll
        for (int ks = 0; ks < 4; ++ks) qf[tt][ks] = *(const s16x8*)(qp + ks * 32);
    }

    float runmax[4] = {NEG_INF, NEG_INF, NEG_INF, NEG_INF};
    float th[4];
    if (PASS == 2) {
        #pragma unroll
        for (int tt = 0; tt < 4; ++tt) th[tt] = theta[(t0 + tt * 16 + lr) * 4 + h];
    }

    // Staging: thread (srow, scol) covers rows srow / srow+16 of each 32-row
    // group, one 16B bf16 chunk each -> coalesced loads, ds_write_b128.
    const int srow = threadIdx.x >> 4;           // 0..15
    const int scol = (threadIdx.x & 15) * 8;     // bf16 elem 0..120
    const unsigned short* kgp =
        Kt + ((size_t)h * 25600 + nb0 + srow) * 128 + scol;
    // group stride = 32 rows * 128 = 4096 bf16; subtile stride = 2048.

    {   // prologue: stage group 0 into buffer 0
        *(s16x8*)&Ks[0][srow][scol]      = *(const s16x8*)kgp;
        *(s16x8*)&Ks[0][srow + 16][scol] = *(const s16x8*)(kgp + 2048);
    }

    for (int g = 0; g < NGRP; ++g) {
        // issue global loads for group g+1 (consumed after this group's MFMAs)
        s16x8 ka0, ka1;
        if (g + 1 < NGRP) {
            const unsigned short* kp = kgp + (size_t)(g + 1) * 4096;
            ka0 = *(const s16x8*)kp;
            ka1 = *(const s16x8*)(kp + 2048);
        }
        __syncthreads();                          // buf[g&1] ready for all waves
        const int cb = g & 1;
        #pragma unroll
        for (int st = 0; st < 2; ++st) {          // 2 expert subtiles of 16
            f32x4 acc[4];
            #pragma unroll
            for (int tt = 0; tt < 4; ++tt) acc[tt] = (f32x4){0.f, 0.f, 0.f, 0.f};
            #pragma unroll
            for (int ks = 0; ks < 4; ++ks) {
                s16x8 ka = *(const s16x8*)&Ks[cb][st * 16 + lr][ks * 32 + lq * 8];
                #pragma unroll
                for (int tt = 0; tt < 4; ++tt)
                    acc[tt] = __builtin_amdgcn_mfma_f32_16x16x32_bf16(ka, qf[tt][ks], acc[tt], 0, 0, 0);
            }
            if (PASS == 1) {
                #pragma unroll
                for (int tt = 0; tt < 4; ++tt) {
                    float m0 = fmaxf(fmaxf(acc[tt][0], acc[tt][1]),
                                     fmaxf(acc[tt][2], acc[tt][3]));
                    runmax[tt] = fmaxf(runmax[tt], m0);
                }
            } else {
                const int nb = nb0 + g * GRP + st * 16;
                #pragma unroll
                for (int tt = 0; tt < 4; ++tt) {
                    float m0 = fmaxf(fmaxf(acc[tt][0], acc[tt][1]),
                                     fmaxf(acc[tt][2], acc[tt][3]));
                    if (m0 >= th[tt]) {
                        int g4 = (t0 + tt * 16 + lr) * 4 + h;
                        #pragma unroll
                        for (int r = 0; r < 4; ++r) {
                            if (acc[tt][r] >= th[tt]) {
                                int n = nb + lq * 4 + r;   // D row = lq*4+r
                                int pos = atomicAdd(&cnt[g4], 1);
                                if (pos < 64) {
                                    float2 e; e.x = acc[tt][r]; e.y = __int_as_float(n);
                                    buf[(size_t)g4 * 64 + pos] = e;
                                }
                            }
                        }
                    }
                }
            }
        }
        // stage group g+1 into the other buffer (vmcnt wait lands here,
        // after this group's MFMAs have issued)
        if (g + 1 < NGRP) {
            const int nbuf = cb ^ 1;
            *(s16x8*)&Ks[nbuf][srow][scol]      = ka0;
            *(s16x8*)&Ks[nbuf][srow + 16][scol] = ka1;
        }
    }

    if (PASS == 1) {
        #pragma unroll
        for (int tt = 0; tt < 4; ++tt)
            maxbuf[(size_t)((t0 + tt * 16 + lr) * 4 + h) * 128 + sp * 4 + lq] = runmax[tt];
    }
}

// ---------------------------------------------------------------------------
// theta = 16th-largest of the 128 cell maxima per (t,h). The 128 cells
// partition all 25600 experts, so >=16 distinct experts score >= theta and
// every true top-16 score is >= theta. Block = 64 threads, grid 128 (spread
// across CUs; r7's 32-block launch left 224 CUs idle).
// ---------------------------------------------------------------------------
__global__ __launch_bounds__(64) void theta_kernel(
        const float* __restrict__ maxbuf, float* __restrict__ theta) {
    int g = blockIdx.x * 64 + threadIdx.x;
    if (g >= 8192) return;
    const float* mb = maxbuf + (size_t)g * 128;
    float s[16];
    #pragma unroll
    for (int i = 0; i < 16; ++i) s[i] = NEG_INF;
    for (int j = 0; j < 128; ++j) {
        float v = mb[j];
        if (v > s[15]) {                 // sorted-desc shift insert
            #pragma unroll
            for (int i = 15; i > 0; --i)
                s[i] = (v > s[i - 1]) ? s[i - 1] : ((v > s[i]) ? v : s[i]);
            s[0] = (v > s[0]) ? v : s[0];
        }
    }
    theta[g] = s[15];
}

// ---------------------------------------------------------------------------
// Finalize, wave-parallel (r8): ONE WAVE per (t,h).
// r7's thread-per-(t,h) version ran 75 us at 1.4% occupancy / 1.4% VALU —
// 32 blocks on 256 CUs, long serial chains. Here:
//  - lane j loads survivor j (coalesced 512B/wave)
//  - exact top-16 via rank: r = #{i : (v_i,n_i) > (v_j,n_j)} (value desc,
//    index asc — same total order as the reference sort; indices distinct
//    so rank is a permutation)
//  - softmax via wave max/sum butterflies
//  - MLP reassociated: comb = sum_j silu(u1_j)*u3_j*c_j with
//    c_j = sum_k aw2[k][j]*gate_k*wup_k ; lanes 0..43 each compute one j,
//    z/w broadcast through a 128B per-wave LDS stripe; wave-reduce -> one
//    atomicAdd per (t,h).
// ---------------------------------------------------------------------------
__global__ __launch_bounds__(256) void finalize_kernel(
        const int* __restrict__ cnt, const float2* __restrict__ buf,
        const float* __restrict__ sumx,
        const float* __restrict__ wdown, const float* __restrict__ wup,
        const float* __restrict__ aw1, const float* __restrict__ aw2,
        const float* __restrict__ aw3, float* __restrict__ combsum) {
    __shared__ float zsh[4][16];
    __shared__ float wsh[4][16];
    const int wv = threadIdx.x >> 6, lane = threadIdx.x & 63;
    const int g = blockIdx.x * 4 + wv;           // (t*4 + h), grid 2048 blocks
    const int t = g >> 2;
    int c = cnt[g]; c = (c > 64) ? 64 : c;       // >=16 guaranteed by theta

    float v = NEG_INF; int n = 0x7fffffff;
    if (lane < c) {
        float2 e = buf[(size_t)g * 64 + lane];
        v = e.x; n = __float_as_int(e.y);
    }
    // rank among survivors (exact tie order: value desc, index asc)
    int r = 0;
    for (int i = 0; i < c; ++i) {
        float vi = __shfl(v, i);
        int   ni = __shfl(n, i);
        r += ((vi > v) || (vi == v && ni < n)) ? 1 : 0;
    }
    // wave max (lanes >= c hold NEG_INF)
    float m = v;
    #pragma unroll
    for (int off = 32; off > 0; off >>= 1) m = fmaxf(m, __shfl_xor(m, off));
    const bool sel = (lane < c) && (r < 16);
    float e = sel ? expf(v - m) : 0.f;
    float den = e;
    #pragma unroll
    for (int off = 32; off > 0; off >>= 1) den += __shfl_xor(den, off);
    if (sel) {
        zsh[wv][r] = sumx[t] * wdown[n];
        wsh[wv][r] = (e / den) * wup[n];
    }
    __syncthreads();
    float contrib = 0.f;
    if (lane < 44) {
        float u1 = 0.f, u3 = 0.f, cj = 0.f;
        #pragma unroll
        for (int k = 0; k < 16; ++k) {
            float zk = zsh[wv][k];
            u1 += zk * aw1[lane * 16 + k];
            u3 += zk * aw3[lane * 16 + k];
            cj += wsh[wv][k] * aw2[k * 44 + lane];
        }
        float gj = u1 / (1.f + expf(-u1)) * u3;
        contrib = gj * cj;
    }
    #pragma unroll
    for (int off = 32; off > 0; off >>= 1) contrib += __shfl_xor(contrib, off);
    if (lane == 0) atomicAdd(&combsum[t], contrib);
}

// ---------------------------------------------------------------------------
// Host launch
// ---------------------------------------------------------------------------
extern "C" void kernel_launch(void* const* d_in, const int* in_sizes, int n_in,
                              void* d_out, int out_size, void* d_ws, size_t ws_size,
                              hipStream_t stream) {
    const float* x     = (const float*)d_in[0];
    const float* wq    = (const float*)d_in[1];
    const float* bq    = (const float*)d_in[2];
    const float* gamma = (const float*)d_in[3];
    const float* beta  = (const float*)d_in[4];
    const float* mean  = (const float*)d_in[5];
    const float* var   = (const float*)d_in[6];
    const float* keys  = (const float*)d_in[7];
    const float* wdown = (const float*)d_in[8];
    const float* wup   = (const float*)d_in[9];
    const float* aw1   = (const float*)d_in[10];
    const float* aw2   = (const float*)d_in[11];
    const float* aw3   = (const float*)d_in[12];
    const float* sw1   = (const float*)d_in[13];
    const float* sw2   = (const float*)d_in[14];
    const float* sw3   = (const float*)d_in[15];
    float* out = (float*)d_out;

    char* ws = (char*)d_ws;
    unsigned short* x_b    = (unsigned short*)(ws + 0);         // 3,145,728 B
    unsigned short* wq_b   = (unsigned short*)(ws + 3145728);   //   786,432
    unsigned short* sw1_b  = (unsigned short*)(ws + 3932160);   // 1,572,864
    unsigned short* sw3_b  = (unsigned short*)(ws + 5505024);   // 1,572,864
    unsigned short* sw2_b  = (unsigned short*)(ws + 7077888);   // 1,572,864
    unsigned short* keys_b = (unsigned short*)(ws + 8650752);   // 26,214,400
    unsigned short* q_b    = (unsigned short*)(ws + 34865152);  // 2,097,152
    float* sumx    = (float*)(ws + 36962304);                   //     8,192
    float* theta   = (float*)(ws + 36970496);                   //    32,768
    float* combsum = (float*)(ws + 37003264);                   //     8,192 } one
    int*   cnt     = (int*)  (ws + 37011456);                   //    32,768 } memset
    // R1 region (4 MB), sequentially reused:
    //   maxbuf (4 MB, pass1 -> theta) -> buf (4 MB, pass2 -> finalize)
    //   -> h_b (4 MB, swiglu -> down-GEMM)
    char* R1 = ws + 37044224;                                   // total ~41 MB
    float* maxbuf = (float*)R1;
    float2* buf   = (float2*)R1;
    unsigned short* h_b = (unsigned short*)R1;

    // one fused bf16 convert (x, wq, sw1, sw3, sw2, keys -> contiguous dst)
    cvt_all_kernel<<<17024, 256, 0, stream>>>(x, wq, sw1, sw3, sw2, keys, x_b);
    row_sum_kernel<<<512, 256, 0, stream>>>(x, sumx);
    hipMemsetAsync(combsum, 0, 40960, stream);   // combsum + cnt (adjacent)

    // q = BN(x @ wq^T + bq) -> bf16 (2048 x 512)
    gemm_nt<0><<<dim3(32, 8), 256, 0, stream>>>(x_b, wq_b, 2048, 512, 768,
                                                nullptr, q_b, bq, gamma, beta, mean, var);
    // pass 1: cell maxima (128 per (t,h))
    score_pass_kernel<1><<<1024, 256, 0, stream>>>(q_b, keys_b, maxbuf, nullptr, nullptr, nullptr);
    // theta = 16th-largest cell max
    theta_kernel<<<128, 64, 0, stream>>>(maxbuf, theta);
    // pass 2: recompute scores, compact survivors >= theta
    score_pass_kernel<2><<<1024, 256, 0, stream>>>(q_b, keys_b, nullptr, theta, cnt, buf);
    // wave-parallel top-16 + gates + tiny MLP -> combsum[t]
    finalize_kernel<<<2048, 256, 0, stream>>>(cnt, buf, sumx, wdown, wup, aw1, aw2, aw3, combsum);
    // dense SwiGLU up (h bf16, 2048 x 1024)
    gemm_swiglu_kernel<<<dim3(32, 16), 256, 0, stream>>>(x_b, sw1_b, sw3_b, 2048, 1024, 768, h_b);
    // down-proj + combsum epilogue -> out fp32 (2048 x 768)
    gemm_nt<2><<<dim3(32, 12), 256, 0, stream>>>(h_b, sw2_b, 2048, 768, 1024,
                                                 out, nullptr, combsum,
                                                 nullptr, nullptr, nullptr, nullptr);
}